// Round 23
// baseline (91.118 us; speedup 1.0000x reference)
//
#include <hip/hip_runtime.h>
#include <hip/hip_fp16.h>
#include <math.h>

#define S 256
#define A 180
#define B 4
#define NSLOT 18285   // LDS dwords: covers y-mode 69x265 and x-mode 264x69

// Single fused kernel: grid (A, 2 batch-pairs, 4 strips), 1024 threads =
// (j=tid>>2, q=tid&3). Adaptive split axis (R20): strip along y if |sn|>=|cs|
// else x -> split coord sweeps at rate >= 0.707, every ray owns ~64..91 taps
// in every strip at every angle. Extreme ownership levels clamped to -1/256
// (R21: outside them both corners are off-image -> exact zero). Packed-f16
// bilinear on (batchA,batchB) pairs (R21). Lane-butterfly epilogue (R22).
// NEW vs R22: staging reads the fp32 input directly (circle mask + f16 pack
// in-register) -- the separate mask/pack kernel and its launch gap are gone;
// output zeroing is a hipMemsetAsync node.
__global__ __launch_bounds__(1024, 8) void radon_lds_kernel(const float* __restrict__ in,
                                                            float* __restrict__ out) {
    __shared__ uint lds[NSLOT];

    const int a = blockIdx.x;   // angle
    const int c = blockIdx.y;   // batch pair
    const int g = blockIdx.z;   // strip
    const int tid = threadIdx.x;

    float ang = (float)a * (float)(M_PI / 179.0);
    float sn, cs;
    sincosf(ang, &sn, &cs);

    const bool ymode = (fabsf(sn) >= fabsf(cs));
    const float rate = ymode ? sn : cs;       // |rate| >= 0.707
    const int wstart = 64 * g - 2;            // split-axis coord in LDS slot 0
    const int st = ymode ? 265 : 69;          // LDS row stride (dwords)

    // ---- stage strip from fp32 global: mask + cvt + pack (zeros outside) ----
    {
        const float* __restrict__ s0 = in + (size_t)(2 * c) * (S * S);
        const float* __restrict__ s1 = s0 + (S * S);
        if (ymode) {
#pragma unroll
            for (int it = 0; it < 18; ++it) {
                int p = it * 1024 + tid;
                if (p < 69 * 264) {
                    int r = p / 264;
                    int c2 = p - r * 264;
                    int y = wstart + r;
                    int x = c2 - 4;
                    uint d = 0u;
                    if (((unsigned)y < 256u) && ((unsigned)x < 256u)) {
                        int dx = x - 128, dy = y - 128;
                        if (dx * dx + dy * dy <= 16384) {
                            float v0 = s0[y * 256 + x];
                            float v1 = s1[y * 256 + x];
                            uint lo = (uint)__half_as_ushort(__float2half(v0));
                            uint hi = (uint)__half_as_ushort(__float2half(v1));
                            d = lo | (hi << 16);
                        }
                    }
                    lds[r * 265 + c2] = d;
                }
            }
        } else {
#pragma unroll
            for (int it = 0; it < 18; ++it) {
                int p = it * 1024 + tid;
                if (p < 264 * 69) {
                    int r = p / 69;
                    int c2 = p - r * 69;
                    int y = r - 4;
                    int x = wstart + c2;
                    uint d = 0u;
                    if (((unsigned)y < 256u) && ((unsigned)x < 256u)) {
                        int dx = x - 128, dy = y - 128;
                        if (dx * dx + dy * dy <= 16384) {
                            float v0 = s0[y * 256 + x];
                            float v1 = s1[y * 256 + x];
                            uint lo = (uint)__half_as_ushort(__float2half(v0));
                            uint hi = (uint)__half_as_ushort(__float2half(v1));
                            d = lo | (hi << 16);
                        }
                    }
                    lds[p] = d;
                }
            }
        }
    }
    __syncthreads();

    const int j = tid >> 2;      // ray index (16 consecutive j per wave)
    const int q = tid & 3;       // per-ray quarter (lane-minor)

    const float ry = (float)j - 127.5f;
    const float bx = fmaf(-sn, ry, 127.5f);
    const float by = fmaf(cs, ry, 127.5f);
    const float ry2 = ry * ry;

    // disk trim (taps beyond d^2>16934 ~130.13^2 are provably zero)
    float hd = sqrtf(16934.0f - ry2);
    int ilo = max((int)ceilf(127.5f - hd), 0);
    int ihi = min((int)floorf(127.5f + hd) + 1, S);

    // strip ownership on w = (ymode ? py : px) = rate*i + w0.
    const float w0 = ymode ? by : bx;
    float invr = 1.0f / rate;
    bool neg = (rate < 0.0f);
    float cLo, cHi;
    if (!neg) {
        cLo = (g == 0) ? -1.0f : (float)(64 * g);
        cHi = (g == 3) ? 256.0f : (float)(64 * g + 64);
    } else {
        cLo = (g == 3) ? 256.0f : (float)(64 * g + 64);
        cHi = (g == 0) ? -1.0f : (float)(64 * g);
    }
    int FLo = (int)fminf(fmaxf(ceilf(127.5f + (cLo - w0) * invr), 0.0f), 256.0f);
    int FHi = (int)fminf(fmaxf(ceilf(127.5f + (cHi - w0) * invr), 0.0f), 256.0f);
    int lo0 = max(ilo, FLo);
    int hi0 = min(ihi, FHi);
    int len = max(hi0 - lo0, 0);
    int lo = lo0 + ((q * len) >> 2);
    int hi = lo0 + (((q + 1) * len) >> 2);

    // folded local coords: px_l = cs*i + bxp, py_l = sn*i + byl
    const float bxp = fmaf(-127.5f, cs, bx) + (ymode ? 4.0f : (float)(-wstart));
    const float byl = fmaf(-127.5f, sn, by) + (ymode ? (float)(-wstart) : 4.0f);

    __half2 acc2 = __floats2half2_rn(0.0f, 0.0f);

#pragma unroll 4
    for (int i = lo; i < hi; ++i) {
        float fi = (float)i;
        float px = fmaf(cs, fi, bxp);
        float py = fmaf(sn, fi, byl);

        float x0f = floorf(px);
        float y0f = floorf(py);
        float wx = px - x0f;
        float wy = py - y0f;
        int xl = (int)x0f;                 // local col (>=0 by margins + clamp)
        int yl = (int)y0f;                 // local row (>=0)
        int addr = yl * st + xl;

        uint d00 = lds[addr];
        uint d10 = lds[addr + 1];
        uint d01 = lds[addr + st];
        uint d11 = lds[addr + st + 1];

        __half2 h00 = __builtin_bit_cast(__half2, d00);
        __half2 h10 = __builtin_bit_cast(__half2, d10);
        __half2 h01 = __builtin_bit_cast(__half2, d01);
        __half2 h11 = __builtin_bit_cast(__half2, d11);

        __half2 wxh = __float2half2_rn(wx);
        __half2 wyh = __float2half2_rn(wy);

        __half2 r0 = __hfma2(wxh, __hsub2(h10, h00), h00);
        __half2 r1 = __hfma2(wxh, __hsub2(h11, h01), h01);
        acc2 = __hfma2(wyh, __hsub2(r1, r0), __hadd2(acc2, r0));
    }

    float accA = __half2float(__low2half(acc2));
    float accB = __half2float(__high2half(acc2));

    // ---- lane-butterfly reduce across the 4 quarter-lanes of ray j ----
    accA += __shfl_xor(accA, 1, 64);
    accB += __shfl_xor(accB, 1, 64);
    accA += __shfl_xor(accA, 2, 64);
    accB += __shfl_xor(accB, 2, 64);
    if (q == 0) {
        size_t o = ((size_t)(2 * c) * A + a) * S + j;
        atomicAdd(&out[o], accA);
        atomicAdd(&out[o + (size_t)A * S], accB);
    }
}

extern "C" void kernel_launch(void* const* d_in, const int* in_sizes, int n_in,
                              void* d_out, int out_size, void* d_ws, size_t ws_size,
                              hipStream_t stream) {
    const float* x = (const float*)d_in[0];
    float* out = (float*)d_out;

    hipMemsetAsync(out, 0, (size_t)out_size * sizeof(float), stream);
    radon_lds_kernel<<<dim3(A, 2, 4), dim3(1024), 0, stream>>>(x, out);
}

// Round 24
// 85.955 us; speedup vs baseline: 1.0601x; 1.0601x over previous
//
#include <hip/hip_runtime.h>
#include <hip/hip_fp16.h>
#include <math.h>

#define S 256
#define A 180
#define B 4
#define NSLOT 18285   // LDS uint2 slots: ymode 69x265, xmode 264x69 (= 146,280 B)

// Kernel 1: circle mask + pack ALL 4 batches per pixel:
// ws[y*256+x] = uint2( f16(b0)|f16(b1)<<16 , f16(b2)|f16(b3)<<16 ).
// Also zeroes the output sinogram (grid 720*256 covers A*B*S = 184,320).
__global__ void radon_mask_pack(const float* __restrict__ in, uint2* __restrict__ ws,
                                float* __restrict__ osino) {
    int idx = blockIdx.x * 256 + threadIdx.x;
    if (idx < S * S) {
        int y = idx >> 8;
        int x = idx & 255;
        int dx = x - 128, dy = y - 128;
        bool inside = (dx * dx + dy * dy <= 16384);
        float v0 = inside ? in[idx] : 0.0f;
        float v1 = inside ? in[S * S + idx] : 0.0f;
        float v2 = inside ? in[2 * S * S + idx] : 0.0f;
        float v3 = inside ? in[3 * S * S + idx] : 0.0f;
        uint lo = (uint)__half_as_ushort(__float2half(v0)) |
                  ((uint)__half_as_ushort(__float2half(v1)) << 16);
        uint hi = (uint)__half_as_ushort(__float2half(v2)) |
                  ((uint)__half_as_ushort(__float2half(v3)) << 16);
        ws[idx] = make_uint2(lo, hi);
    }
    if (idx < A * B * S) osino[idx] = 0.0f;
}

// Kernel 2: grid (A, 1, 4 strips), 1024 thr = (j=tid>>2, q=tid&3). Adaptive
// split axis (R20), extreme-level clamp to -1/256 (R21), packed-f16 bilinear
// (R21), shfl-butterfly epilogue (R22). NEW: all 4 batches per tap -- pixel =
// uint2, row-corner fetch = ds_read2_b64-shaped (2 insts / 8 dwords), so
// address+weight VALU and LDS cycles are amortized 4x instead of 2x.
// 146 KB LDS -> 1 block/CU (16 waves; fine per R14).
__global__ __launch_bounds__(1024, 4) void radon_lds_kernel(const uint2* __restrict__ ws,
                                                            float* __restrict__ out) {
    __shared__ uint2 lds2[NSLOT];

    const int a = blockIdx.x;   // angle
    const int g = blockIdx.z;   // strip
    const int tid = threadIdx.x;

    float ang = (float)a * (float)(M_PI / 179.0);
    float sn, cs;
    sincosf(ang, &sn, &cs);

    const bool ymode = (fabsf(sn) >= fabsf(cs));
    const float rate = ymode ? sn : cs;       // |rate| >= 0.707
    const int wstart = 64 * g - 2;            // split-axis coord in LDS slot 0
    const int st = ymode ? 265 : 69;          // LDS row stride (uint2 slots)

    // ---- stage strip (zeros outside image); wave-uniform mode branch ----
    if (ymode) {
#pragma unroll
        for (int it = 0; it < 18; ++it) {
            int p = it * 1024 + tid;
            if (p < 69 * 264) {
                int r = p / 264;
                int c2 = p - r * 264;
                int y = wstart + r;
                int x = c2 - 4;
                uint2 d = make_uint2(0u, 0u);
                if (((unsigned)y < 256u) && ((unsigned)x < 256u)) d = ws[y * 256 + x];
                lds2[r * 265 + c2] = d;
            }
        }
    } else {
#pragma unroll
        for (int it = 0; it < 18; ++it) {
            int p = it * 1024 + tid;
            if (p < 264 * 69) {
                int r = p / 69;
                int c2 = p - r * 69;
                int y = r - 4;
                int x = wstart + c2;
                uint2 d = make_uint2(0u, 0u);
                if (((unsigned)y < 256u) && ((unsigned)x < 256u)) d = ws[y * 256 + x];
                lds2[p] = d;
            }
        }
    }
    __syncthreads();

    const int j = tid >> 2;      // ray index (16 consecutive j per wave)
    const int q = tid & 3;       // per-ray quarter (lane-minor)

    const float ry = (float)j - 127.5f;
    const float bx = fmaf(-sn, ry, 127.5f);
    const float by = fmaf(cs, ry, 127.5f);
    const float ry2 = ry * ry;

    // disk trim (taps beyond d^2>16934 ~130.13^2 are provably zero)
    float hd = sqrtf(16934.0f - ry2);
    int ilo = max((int)ceilf(127.5f - hd), 0);
    int ihi = min((int)floorf(127.5f + hd) + 1, S);

    // strip ownership on w = (ymode ? py : px) = rate*i + w0.
    const float w0 = ymode ? by : bx;
    float invr = 1.0f / rate;
    bool neg = (rate < 0.0f);
    float cLo, cHi;
    if (!neg) {
        cLo = (g == 0) ? -1.0f : (float)(64 * g);
        cHi = (g == 3) ? 256.0f : (float)(64 * g + 64);
    } else {
        cLo = (g == 3) ? 256.0f : (float)(64 * g + 64);
        cHi = (g == 0) ? -1.0f : (float)(64 * g);
    }
    int FLo = (int)fminf(fmaxf(ceilf(127.5f + (cLo - w0) * invr), 0.0f), 256.0f);
    int FHi = (int)fminf(fmaxf(ceilf(127.5f + (cHi - w0) * invr), 0.0f), 256.0f);
    int lo0 = max(ilo, FLo);
    int hi0 = min(ihi, FHi);
    int len = max(hi0 - lo0, 0);
    int lo = lo0 + ((q * len) >> 2);
    int hi = lo0 + (((q + 1) * len) >> 2);

    // folded local coords: px_l = cs*i + bxp, py_l = sn*i + byl
    const float bxp = fmaf(-127.5f, cs, bx) + (ymode ? 4.0f : (float)(-wstart));
    const float byl = fmaf(-127.5f, sn, by) + (ymode ? (float)(-wstart) : 4.0f);

    __half2 accP = __floats2half2_rn(0.0f, 0.0f);   // batches 0,1
    __half2 accQ = __floats2half2_rn(0.0f, 0.0f);   // batches 2,3

#pragma unroll 4
    for (int i = lo; i < hi; ++i) {
        float fi = (float)i;
        float px = fmaf(cs, fi, bxp);
        float py = fmaf(sn, fi, byl);

        float x0f = floorf(px);
        float y0f = floorf(py);
        float wx = px - x0f;
        float wy = py - y0f;
        int xl = (int)x0f;                 // local col (>=0 by margins + clamp)
        int yl = (int)y0f;                 // local row (>=0)
        int addr = yl * st + xl;

        uint2 d00 = lds2[addr];            // pixel (x0  ,y0): (b01, b23)
        uint2 d10 = lds2[addr + 1];        // pixel (x0+1,y0)
        uint2 d01 = lds2[addr + st];       // pixel (x0  ,y0+1)
        uint2 d11 = lds2[addr + st + 1];   // pixel (x0+1,y0+1)

        __half2 wxh = __float2half2_rn(wx);
        __half2 wyh = __float2half2_rn(wy);

        __half2 p00 = __builtin_bit_cast(__half2, d00.x);
        __half2 p10 = __builtin_bit_cast(__half2, d10.x);
        __half2 p01 = __builtin_bit_cast(__half2, d01.x);
        __half2 p11 = __builtin_bit_cast(__half2, d11.x);
        __half2 r0 = __hfma2(wxh, __hsub2(p10, p00), p00);
        __half2 r1 = __hfma2(wxh, __hsub2(p11, p01), p01);
        accP = __hfma2(wyh, __hsub2(r1, r0), __hadd2(accP, r0));

        __half2 s00 = __builtin_bit_cast(__half2, d00.y);
        __half2 s10 = __builtin_bit_cast(__half2, d10.y);
        __half2 s01 = __builtin_bit_cast(__half2, d01.y);
        __half2 s11 = __builtin_bit_cast(__half2, d11.y);
        __half2 t0 = __hfma2(wxh, __hsub2(s10, s00), s00);
        __half2 t1 = __hfma2(wxh, __hsub2(s11, s01), s01);
        accQ = __hfma2(wyh, __hsub2(t1, t0), __hadd2(accQ, t0));
    }

    float a0 = __half2float(__low2half(accP));
    float a1 = __half2float(__high2half(accP));
    float a2 = __half2float(__low2half(accQ));
    float a3 = __half2float(__high2half(accQ));

    // ---- lane-butterfly reduce across the 4 quarter-lanes of ray j ----
    a0 += __shfl_xor(a0, 1, 64);  a1 += __shfl_xor(a1, 1, 64);
    a2 += __shfl_xor(a2, 1, 64);  a3 += __shfl_xor(a3, 1, 64);
    a0 += __shfl_xor(a0, 2, 64);  a1 += __shfl_xor(a1, 2, 64);
    a2 += __shfl_xor(a2, 2, 64);  a3 += __shfl_xor(a3, 2, 64);
    if (q == 0) {
        size_t o = (size_t)a * S + j;
        const size_t stride = (size_t)A * S;
        atomicAdd(&out[o], a0);
        atomicAdd(&out[o + stride], a1);
        atomicAdd(&out[o + 2 * stride], a2);
        atomicAdd(&out[o + 3 * stride], a3);
    }
}

extern "C" void kernel_launch(void* const* d_in, const int* in_sizes, int n_in,
                              void* d_out, int out_size, void* d_ws, size_t ws_size,
                              hipStream_t stream) {
    const float* x = (const float*)d_in[0];
    float* out = (float*)d_out;
    uint2* ws = (uint2*)d_ws;  // 65,536 uint2 = 512 KiB

    radon_mask_pack<<<dim3(720), dim3(256), 0, stream>>>(x, ws, out);
    radon_lds_kernel<<<dim3(A, 1, 4), dim3(1024), 0, stream>>>(ws, out);
}